// Round 6
// baseline (83.513 us; speedup 1.0000x reference)
//
#include <hip/hip_runtime.h>

#define HH 224
#define WW 224
#define NXCD 8
#define PPT 4  // pixels per thread

// out[b,y,x,c] = sbp[b, Yi, Xi, c]
//   Yi = int((y + dy) mod H)  (jnp.remainder semantics), clamped to H-1
//   Xi = int((x + dx) mod W), clamped to W-1
//   sbp border = 0; interior = 0.25*(tl+tr+bl+br) of img (channels 0..2).
__global__ __launch_bounds__(256) void bilinear_gather_kernel(
    const float* __restrict__ x, float* __restrict__ out,
    int nthreads /* total/PPT */, int nwg) {
    // XCD-aware bijective swizzle: each XCD gets a contiguous slab of logical
    // blocks so gather-neighbor rows share one per-XCD L2 (round 3->4: 2.2x).
    int p = blockIdx.x;
    int xcd = p % NXCD;
    int idx = p / NXCD;
    int q = nwg / NXCD;
    int r = nwg % NXCD;
    int lb = (xcd < r ? xcd * (q + 1) : r * (q + 1) + (xcd - r) * q) + idx;

    int tid = lb * blockDim.x + threadIdx.x;
    if (tid >= nthreads) return;
    int i0 = tid * PPT;

    float res[3 * PPT];

#pragma unroll
    for (int k = 0; k < PPT; ++k) {
        int i = i0 + k;
        int px = i % WW;
        int t  = i / WW;
        int py = t % HH;
        int b  = t / HH;

        const float* pix = x + (size_t)i * 5;
        float dx = pix[3];
        float dy = pix[4];

        // jnp.remainder: trunc fmod, then +W if result negative.
        float rx = fmodf((float)px + dx, (float)WW);
        if (rx < 0.f) rx += (float)WW;   // may round to exactly 224.0
        float ry = fmodf((float)py + dy, (float)HH);
        if (ry < 0.f) ry += (float)HH;

        int xi = (int)rx; if (xi > WW - 1) xi = WW - 1;  // JAX clamps OOB
        int yi = (int)ry; if (yi > HH - 1) yi = HH - 1;

        float r0 = 0.f, g0 = 0.f, b0 = 0.f;
        if (xi >= 1 && xi <= WW - 2 && yi >= 1 && yi <= HH - 2) {
            const float* base = x + (size_t)b * HH * WW * 5;
            const float* p00 = base + ((size_t)(yi - 1) * WW + (xi - 1)) * 5;
            const float* p01 = base + ((size_t)(yi - 1) * WW + (xi + 1)) * 5;
            const float* p10 = base + ((size_t)(yi + 1) * WW + (xi - 1)) * 5;
            const float* p11 = base + ((size_t)(yi + 1) * WW + (xi + 1)) * 5;
            r0 = 0.25f * (p00[0] + p01[0] + p10[0] + p11[0]);
            g0 = 0.25f * (p00[1] + p01[1] + p10[1] + p11[1]);
            b0 = 0.25f * (p00[2] + p01[2] + p10[2] + p11[2]);
        }
        res[k * 3 + 0] = r0;
        res[k * 3 + 1] = g0;
        res[k * 3 + 2] = b0;
    }

    // 12 contiguous floats per thread -> 3 aligned float4 stores (48 B/lane).
    float4* o = (float4*)(out + (size_t)i0 * 3);
    o[0] = make_float4(res[0], res[1], res[2], res[3]);
    o[1] = make_float4(res[4], res[5], res[6], res[7]);
    o[2] = make_float4(res[8], res[9], res[10], res[11]);
}

extern "C" void kernel_launch(void* const* d_in, const int* in_sizes, int n_in,
                              void* d_out, int out_size, void* d_ws, size_t ws_size,
                              hipStream_t stream) {
    const float* x = (const float*)d_in[0];
    float* out = (float*)d_out;
    int total = in_sizes[0] / 5;       // B*H*W = 6422528, divisible by PPT*256
    int nthreads = total / PPT;
    int blocks = (nthreads + 255) / 256;
    bilinear_gather_kernel<<<blocks, 256, 0, stream>>>(x, out, nthreads, blocks);
}

// Round 8
// 48.155 us; speedup vs baseline: 1.7343x; 1.7343x over previous
//
#include <hip/hip_runtime.h>

#define HH 224
#define WW 224
#define NXCD 8
#define PPT 4  // pixels per thread, interleaved at wave stride

// out[b,y,x,c] = sbp[b, Yi, Xi, c]
//   Yi = int((y + dy) mod H)  (jnp.remainder semantics), clamped to H-1
//   Xi = int((x + dx) mod W), clamped to W-1
//   sbp border = 0; interior = 0.25*(tl+tr+bl+br) of img (channels 0..2).
__global__ __launch_bounds__(256) void bilinear_gather_kernel(
    const float* __restrict__ x, float* __restrict__ out,
    int total, int nwg) {
    // XCD-aware bijective swizzle: each XCD gets a contiguous slab of logical
    // blocks so gather-neighbor rows share one per-XCD L2 (round 3->4: 2.2x).
    int p = blockIdx.x;
    int xcd = p % NXCD;
    int idx = p / NXCD;
    int q = nwg / NXCD;
    int r = nwg % NXCD;
    int lb = (xcd < r ? xcd * (q + 1) : r * (q + 1) + (xcd - r) * q) + idx;

    // Block owns PPT*256 consecutive pixels; thread t handles base + t + 256*k.
    // Lane-to-lane stride stays 20 B (round 6 lesson: consecutive-per-thread
    // quadrupled lines-touched-per-instruction and regressed 1.8x).
    int base = lb * (PPT * 256) + threadIdx.x;

    float res[3 * PPT];

#pragma unroll
    for (int k = 0; k < PPT; ++k) {
        int i = base + k * 256;
        // total = B*H*W is divisible by PPT*256, so i < total always; no guard.
        int px = i % WW;
        int t  = i / WW;
        int py = t % HH;
        int b  = t / HH;

        const float* pix = x + (size_t)i * 5;
        float dx = pix[3];
        float dy = pix[4];

        // jnp.remainder: trunc fmod, then +W if result negative.
        float rx = fmodf((float)px + dx, (float)WW);
        if (rx < 0.f) rx += (float)WW;   // may round to exactly 224.0
        float ry = fmodf((float)py + dy, (float)HH);
        if (ry < 0.f) ry += (float)HH;

        int xi = (int)rx; if (xi > WW - 1) xi = WW - 1;  // JAX clamps OOB
        int yi = (int)ry; if (yi > HH - 1) yi = HH - 1;

        // Mask instead of branch: taps always loaded (clamped to interior) so
        // the 4 iterations' 16 loads form independent, hoistable chains.
        float m = (xi >= 1 && xi <= WW - 2 && yi >= 1 && yi <= HH - 2) ? 0.25f : 0.f;
        int xc = xi < 1 ? 1 : (xi > WW - 2 ? WW - 2 : xi);
        int yc = yi < 1 ? 1 : (yi > HH - 2 ? HH - 2 : yi);

        const float* bb = x + (size_t)b * HH * WW * 5;
        const float* p00 = bb + ((size_t)(yc - 1) * WW + (xc - 1)) * 5;
        const float* p01 = bb + ((size_t)(yc - 1) * WW + (xc + 1)) * 5;
        const float* p10 = bb + ((size_t)(yc + 1) * WW + (xc - 1)) * 5;
        const float* p11 = bb + ((size_t)(yc + 1) * WW + (xc + 1)) * 5;
        res[k * 3 + 0] = m * (p00[0] + p01[0] + p10[0] + p11[0]);
        res[k * 3 + 1] = m * (p00[1] + p01[1] + p10[1] + p11[1]);
        res[k * 3 + 2] = m * (p00[2] + p01[2] + p10[2] + p11[2]);
    }

#pragma unroll
    for (int k = 0; k < PPT; ++k) {
        int i = base + k * 256;
        float* o = out + (size_t)i * 3;
        o[0] = res[k * 3 + 0];
        o[1] = res[k * 3 + 1];
        o[2] = res[k * 3 + 2];
    }
}

extern "C" void kernel_launch(void* const* d_in, const int* in_sizes, int n_in,
                              void* d_out, int out_size, void* d_ws, size_t ws_size,
                              hipStream_t stream) {
    const float* x = (const float*)d_in[0];
    float* out = (float*)d_out;
    int total = in_sizes[0] / 5;        // B*H*W = 6422528 = 6272 * 1024
    int blocks = total / (PPT * 256);
    bilinear_gather_kernel<<<blocks, 256, 0, stream>>>(x, out, total, blocks);
}